// Round 1
// baseline (899.593 us; speedup 1.0000x reference)
//
#include <hip/hip_runtime.h>
#include <cstdint>
#include <cstddef>

typedef __bf16 bf16x8 __attribute__((ext_vector_type(8)));
typedef float f32x4 __attribute__((ext_vector_type(4)));

#define SEQ   4096
#define HID   1280
#define NH    16
#define HD    80
#define NQKV  3840

__device__ __forceinline__ unsigned short f2bf(float f) {
  unsigned int u = __float_as_uint(f);
  unsigned int r = u + 0x7FFFu + ((u >> 16) & 1u);   // RNE
  return (unsigned short)(r >> 16);
}
__device__ __forceinline__ float bf2f(unsigned short h) {
  return __uint_as_float(((unsigned int)h) << 16);
}

// ---------------- split: f32 -> bf16 hi + bf16 lo (x = hi + lo to ~2^-18) ----
__global__ __launch_bounds__(256) void split_kernel(const float* __restrict__ x,
                                                    unsigned short* __restrict__ hi,
                                                    unsigned short* __restrict__ lo,
                                                    int n4) {
  int i = blockIdx.x * 256 + threadIdx.x;
  if (i >= n4) return;
  float4 v = *((const float4*)x + i);
  float vv[4] = {v.x, v.y, v.z, v.w};
  unsigned short hh[4], ll[4];
#pragma unroll
  for (int j = 0; j < 4; ++j) {
    hh[j] = f2bf(vv[j]);
    ll[j] = f2bf(vv[j] - bf2f(hh[j]));
  }
  *((ushort4*)hi + i) = make_ushort4(hh[0], hh[1], hh[2], hh[3]);
  *((ushort4*)lo + i) = make_ushort4(ll[0], ll[1], ll[2], ll[3]);
}

// ---------------- transpose + split: W (K x N f32) -> W^T hi/lo (N x K bf16) --
__global__ __launch_bounds__(256) void tsplit_kernel(const float* __restrict__ W,
                                                     unsigned short* __restrict__ Thi,
                                                     unsigned short* __restrict__ Tlo,
                                                     int K, int N) {
  __shared__ float tile[32][33];
  int n0 = blockIdx.x * 32, k0 = blockIdx.y * 32;
  int tx = threadIdx.x & 31, ty = threadIdx.x >> 5;
#pragma unroll
  for (int i = 0; i < 32; i += 8)
    tile[ty + i][tx] = W[(size_t)(k0 + ty + i) * N + n0 + tx];
  __syncthreads();
#pragma unroll
  for (int i = 0; i < 32; i += 8) {
    float v = tile[tx][ty + i];
    size_t idx = (size_t)(n0 + ty + i) * K + (size_t)(k0 + tx);
    unsigned short h = f2bf(v);
    Thi[idx] = h;
    Tlo[idx] = f2bf(v - bf2f(h));
  }
}

// ---------------- GEMM: C = A*B + bias, bf16x3 (fp32-accurate) ---------------
// A given as Ah/Al: M x K bf16 (row major). B given as Bh/Bl: N x K bf16 (i.e.
// W^T row-major). C: M x N f32. M,N,K multiples of 64.
// Block 256 thr = 4 waves (2x2), 64x64 tile, BK=64, mfma_f32_16x16x32_bf16.
__global__ __launch_bounds__(256) void gemm_x3_kernel(
    const unsigned short* __restrict__ Ah, const unsigned short* __restrict__ Al,
    const unsigned short* __restrict__ Bh, const unsigned short* __restrict__ Bl,
    const float* __restrict__ bias, float* __restrict__ C,
    int M, int N, int K) {
  __shared__ __align__(16) unsigned short sAh[64][72];
  __shared__ __align__(16) unsigned short sAl[64][72];
  __shared__ __align__(16) unsigned short sBh[64][72];
  __shared__ __align__(16) unsigned short sBl[64][72];

  const int t = threadIdx.x;
  const int bm = blockIdx.y * 64, bn = blockIdx.x * 64;
  const int lane = t & 63, wave = t >> 6;
  const int wr = (wave >> 1) * 32, wc = (wave & 1) * 32;
  const int row16 = lane & 15, quad = lane >> 4;

  f32x4 acc[2][2];
#pragma unroll
  for (int i = 0; i < 2; ++i)
#pragma unroll
    for (int j = 0; j < 2; ++j) acc[i][j] = (f32x4){0.f, 0.f, 0.f, 0.f};

  const int r0 = t >> 3, c80 = (t & 7) * 8;
  const int r1 = (t + 256) >> 3;  // (t+256)&7 == t&7

  const unsigned short* pAh = Ah + (size_t)bm * K;
  const unsigned short* pAl = Al + (size_t)bm * K;
  const unsigned short* pBh = Bh + (size_t)bn * K;
  const unsigned short* pBl = Bl + (size_t)bn * K;

  for (int k0 = 0; k0 < K; k0 += 64) {
    __syncthreads();
    *(uint4*)&sAh[r0][c80] = *(const uint4*)(pAh + (size_t)r0 * K + k0 + c80);
    *(uint4*)&sAh[r1][c80] = *(const uint4*)(pAh + (size_t)r1 * K + k0 + c80);
    *(uint4*)&sAl[r0][c80] = *(const uint4*)(pAl + (size_t)r0 * K + k0 + c80);
    *(uint4*)&sAl[r1][c80] = *(const uint4*)(pAl + (size_t)r1 * K + k0 + c80);
    *(uint4*)&sBh[r0][c80] = *(const uint4*)(pBh + (size_t)r0 * K + k0 + c80);
    *(uint4*)&sBh[r1][c80] = *(const uint4*)(pBh + (size_t)r1 * K + k0 + c80);
    *(uint4*)&sBl[r0][c80] = *(const uint4*)(pBl + (size_t)r0 * K + k0 + c80);
    *(uint4*)&sBl[r1][c80] = *(const uint4*)(pBl + (size_t)r1 * K + k0 + c80);
    __syncthreads();
#pragma unroll
    for (int ks = 0; ks < 64; ks += 32) {
      bf16x8 ah[2], al[2], bh[2], bl[2];
#pragma unroll
      for (int mi = 0; mi < 2; ++mi) {
        ah[mi] = *(const bf16x8*)&sAh[wr + mi * 16 + row16][ks + quad * 8];
        al[mi] = *(const bf16x8*)&sAl[wr + mi * 16 + row16][ks + quad * 8];
      }
#pragma unroll
      for (int ni = 0; ni < 2; ++ni) {
        bh[ni] = *(const bf16x8*)&sBh[wc + ni * 16 + row16][ks + quad * 8];
        bl[ni] = *(const bf16x8*)&sBl[wc + ni * 16 + row16][ks + quad * 8];
      }
#pragma unroll
      for (int mi = 0; mi < 2; ++mi)
#pragma unroll
        for (int ni = 0; ni < 2; ++ni) {
          acc[mi][ni] = __builtin_amdgcn_mfma_f32_16x16x32_bf16(ah[mi], bh[ni], acc[mi][ni], 0, 0, 0);
          acc[mi][ni] = __builtin_amdgcn_mfma_f32_16x16x32_bf16(ah[mi], bl[ni], acc[mi][ni], 0, 0, 0);
          acc[mi][ni] = __builtin_amdgcn_mfma_f32_16x16x32_bf16(al[mi], bh[ni], acc[mi][ni], 0, 0, 0);
        }
    }
  }
  // epilogue: C/D layout col=lane&15, row=quad*4+reg (m89-verified)
#pragma unroll
  for (int mi = 0; mi < 2; ++mi)
#pragma unroll
    for (int ni = 0; ni < 2; ++ni) {
      int col = bn + wc + ni * 16 + row16;
      float bv = bias[col];
#pragma unroll
      for (int r = 0; r < 4; ++r) {
        int rowg = bm + wr + mi * 16 + quad * 4 + r;
        C[(size_t)rowg * N + col] = acc[mi][ni][r] + bv;
      }
    }
}

// ---------------- RoPE in-place on q and k parts of qkv ----------------------
// one thread per (s, qk, h, d<40) pair
__global__ __launch_bounds__(256) void rope_kernel(float* __restrict__ qkv,
                                                   const float* __restrict__ cs,
                                                   const float* __restrict__ sn) {
  int idx = blockIdx.x * 256 + threadIdx.x;  // < 4096*2*16*40
  int d = idx % 40;
  int rest = idx / 40;
  int h = rest % 16; rest /= 16;
  int qk = rest & 1;
  int s = rest >> 1;
  float* base = qkv + (size_t)s * NQKV + qk * HID + h * HD;
  float c0 = cs[s * HD + d],      s0 = sn[s * HD + d];
  float c1 = cs[s * HD + d + 40], s1 = sn[s * HD + d + 40];
  float x0 = base[d], x1 = base[d + 40];
  base[d]      = x0 * c0 - x1 * s0;
  base[d + 40] = x1 * c1 + x0 * s1;
}

// ---------------- attention: fp32 online-softmax, segment-masked -------------
// grid (64 q-tiles of 64 rows, 16 heads), 256 threads.
__global__ __launch_bounds__(256) void attn_kernel(const float* __restrict__ qkv,
                                                   const int* __restrict__ cu,
                                                   float* __restrict__ o) {
  __shared__ __align__(16) float sQ[64][84];
  __shared__ __align__(16) float sKV[5440];   // union: K [64][84] then V^T [80][68]
  __shared__ __align__(16) float sS[64][68];
  __shared__ int segq[64], segk[64];
  __shared__ float mrow[64], lrow[64], crow[64];
  __shared__ int cu_s[9];

  const int h = blockIdx.y;
  const int r0 = blockIdx.x * 64;
  const int t = threadIdx.x;

  if (t < 9) cu_s[t] = cu[t];
  __syncthreads();
  if (t < 64) {
    int pos = r0 + t;
    int sg = 0;
#pragma unroll
    for (int i = 1; i < 8; ++i) sg += (pos >= cu_s[i]) ? 1 : 0;
    segq[t] = sg;
    mrow[t] = -1e30f; lrow[t] = 0.0f; crow[t] = 1.0f;
  }
  {  // stage Q (post-RoPE)
    int row = t >> 2, db = (t & 3) * 20;
    const float* src = qkv + (size_t)(r0 + row) * NQKV + h * HD + db;
#pragma unroll
    for (int i = 0; i < 5; ++i)
      *(float4*)&sQ[row][db + 4 * i] = *(const float4*)(src + 4 * i);
  }
  __syncthreads();
  const int kstart = cu_s[segq[0]];
  const int kend   = cu_s[segq[63] + 1];

  float O[4][5];
#pragma unroll
  for (int m = 0; m < 4; ++m)
#pragma unroll
    for (int c = 0; c < 5; ++c) O[m][c] = 0.f;

  const int qig = t >> 4, dg = t & 15;   // also scores mapping qi0/kj0
  const int srow = t >> 2, sp = t & 3;

  for (int ck = kstart; ck < kend; ck += 64) {
    __syncthreads();  // protect sKV from previous PV readers
    {  // stage K chunk as K[64][84]
      int row = t >> 2, db = (t & 3) * 20;
      int tr = ck + row; if (tr > SEQ - 1) tr = SEQ - 1;
      const float* src = qkv + (size_t)tr * NQKV + HID + h * HD + db;
      float* dst = &sKV[row * 84 + db];
#pragma unroll
      for (int i = 0; i < 5; ++i)
        *(float4*)(dst + 4 * i) = *(const float4*)(src + 4 * i);
    }
    if (t < 64) {
      int tk = ck + t;
      int sg = -1;
      if (tk < kend) {
        sg = 0;
#pragma unroll
        for (int i = 1; i < 8; ++i) sg += (tk >= cu_s[i]) ? 1 : 0;
      }
      segk[t] = sg;
    }
    __syncthreads();
    {  // scores: thread = (qi0 = t>>4, kj0 = t&15), 4x4 interleaved by 16
      float sc[4][4];
#pragma unroll
      for (int m = 0; m < 4; ++m)
#pragma unroll
        for (int n = 0; n < 4; ++n) sc[m][n] = 0.f;
      for (int d = 0; d < 80; d += 4) {
        float4 qv[4], kv[4];
#pragma unroll
        for (int m = 0; m < 4; ++m) qv[m] = *(const float4*)&sQ[qig + 16 * m][d];
#pragma unroll
        for (int n = 0; n < 4; ++n) kv[n] = *(const float4*)&sKV[(dg + 16 * n) * 84 + d];
#pragma unroll
        for (int m = 0; m < 4; ++m)
#pragma unroll
          for (int n = 0; n < 4; ++n)
            sc[m][n] += qv[m].x * kv[n].x + qv[m].y * kv[n].y +
                        qv[m].z * kv[n].z + qv[m].w * kv[n].w;
      }
      const float scale = 0.11180339887498949f;  // 80^-0.5
#pragma unroll
      for (int m = 0; m < 4; ++m)
#pragma unroll
        for (int n = 0; n < 4; ++n) {
          int qi = qig + 16 * m, kj = dg + 16 * n;
          sS[qi][kj] = (segk[kj] == segq[qi]) ? sc[m][n] * scale : -1e30f;
        }
    }
    __syncthreads();
    {  // online softmax: thread = (row = t>>2, quarter sp), 16 scores each
      float4 sv[4];
#pragma unroll
      for (int i = 0; i < 4; ++i) sv[i] = *(const float4*)&sS[srow][sp * 16 + 4 * i];
      float mx = -1e30f;
#pragma unroll
      for (int i = 0; i < 4; ++i)
        mx = fmaxf(mx, fmaxf(fmaxf(sv[i].x, sv[i].y), fmaxf(sv[i].z, sv[i].w)));
      mx = fmaxf(mx, __shfl_xor(mx, 1));
      mx = fmaxf(mx, __shfl_xor(mx, 2));
      float mold = mrow[srow];
      float mnew = fmaxf(mold, mx);
      float corr = __expf(mold - mnew);
      float psum = 0.f;
#pragma unroll
      for (int i = 0; i < 4; ++i) {
        sv[i].x = (sv[i].x > -1e29f) ? __expf(sv[i].x - mnew) : 0.f; psum += sv[i].x;
        sv[i].y = (sv[i].y > -1e29f) ? __expf(sv[i].y - mnew) : 0.f; psum += sv[i].y;
        sv[i].z = (sv[i].z > -1e29f) ? __expf(sv[i].z - mnew) : 0.f; psum += sv[i].z;
        sv[i].w = (sv[i].w > -1e29f) ? __expf(sv[i].w - mnew) : 0.f; psum += sv[i].w;
      }
      psum += __shfl_xor(psum, 1);
      psum += __shfl_xor(psum, 2);
#pragma unroll
      for (int i = 0; i < 4; ++i) *(float4*)&sS[srow][sp * 16 + 4 * i] = sv[i];
      if (sp == 0) {
        mrow[srow] = mnew;
        lrow[srow] = lrow[srow] * corr + psum;
        crow[srow] = corr;
      }
    }
    __syncthreads();
    {  // stage V^T [80][68] over the K buffer (K is dead now)
      int row = t >> 2, db = (t & 3) * 20;
      int tr = ck + row; if (tr > SEQ - 1) tr = SEQ - 1;
      const float* src = qkv + (size_t)tr * NQKV + 2 * HID + h * HD + db;
      float tmp[20];
#pragma unroll
      for (int i = 0; i < 5; ++i) {
        float4 v = *(const float4*)(src + 4 * i);
        tmp[4 * i] = v.x; tmp[4 * i + 1] = v.y; tmp[4 * i + 2] = v.z; tmp[4 * i + 3] = v.w;
      }
#pragma unroll
      for (int i = 0; i < 20; ++i)
        sKV[(db + i) * 68 + row] = tmp[i];
    }
    __syncthreads();
    {  // PV: thread = (qig rows {+0,16,32,48}, dg -> d = dg*5..+4)
      float cr[4];
#pragma unroll
      for (int m = 0; m < 4; ++m) cr[m] = crow[qig + 16 * m];
#pragma unroll
      for (int m = 0; m < 4; ++m)
#pragma unroll
        for (int c = 0; c < 5; ++c) O[m][c] *= cr[m];
      for (int j0 = 0; j0 < 64; j0 += 4) {
        float4 pv[4], vv[5];
#pragma unroll
        for (int m = 0; m < 4; ++m) pv[m] = *(const float4*)&sS[qig + 16 * m][j0];
#pragma unroll
        for (int c = 0; c < 5; ++c) vv[c] = *(const float4*)&sKV[(dg * 5 + c) * 68 + j0];
#pragma unroll
        for (int m = 0; m < 4; ++m)
#pragma unroll
          for (int c = 0; c < 5; ++c)
            O[m][c] += pv[m].x * vv[c].x + pv[m].y * vv[c].y +
                       pv[m].z * vv[c].z + pv[m].w * vv[c].w;
      }
    }
  }
  __syncthreads();
  {  // normalize + store
#pragma unroll
    for (int m = 0; m < 4; ++m) {
      float inv = 1.0f / lrow[qig + 16 * m];
      size_t base = (size_t)(r0 + qig + 16 * m) * HID + h * HD + dg * 5;
#pragma unroll
      for (int c = 0; c < 5; ++c)
        o[base + c] = O[m][c] * inv;
    }
  }
}

// ---------------- host launcher ---------------------------------------------
extern "C" void kernel_launch(void* const* d_in, const int* in_sizes, int n_in,
                              void* d_out, int out_size, void* d_ws, size_t ws_size,
                              hipStream_t stream) {
  const float* x      = (const float*)d_in[0];
  const int*   cu     = (const int*)d_in[1];
  const float* cs     = (const float*)d_in[2];
  const float* sn     = (const float*)d_in[3];
  const float* w_qkv  = (const float*)d_in[4];
  const float* b_qkv  = (const float*)d_in[5];
  const float* w_proj = (const float*)d_in[6];
  const float* b_proj = (const float*)d_in[7];
  float* out = (float*)d_out;

  char* ws = (char*)d_ws;
  // layout (bytes):
  //   [0, 62914560)            qkv f32            (later reused for o_hi/o_lo)
  //   [62914560, 83886080)     x_hi/x_lo bf16     (later reused for o f32)
  //   [83886080, 103546880)    wqkvT hi/lo bf16
  //   [103546880, 110100480)   wprojT hi/lo bf16
  float*          qkv    = (float*)(ws + 0);
  unsigned short* x_hi   = (unsigned short*)(ws + 62914560ULL);
  unsigned short* x_lo   = (unsigned short*)(ws + 73400320ULL);
  unsigned short* wqt_hi = (unsigned short*)(ws + 83886080ULL);
  unsigned short* wqt_lo = (unsigned short*)(ws + 93716480ULL);
  unsigned short* wpt_hi = (unsigned short*)(ws + 103546880ULL);
  unsigned short* wpt_lo = (unsigned short*)(ws + 106823680ULL);
  float*          obuf   = (float*)(ws + 62914560ULL);      // over dead x_hi/x_lo
  unsigned short* o_hi   = (unsigned short*)(ws + 0);       // over dead qkv
  unsigned short* o_lo   = (unsigned short*)(ws + 10485760ULL);

  split_kernel<<<5120, 256, 0, stream>>>(x, x_hi, x_lo, 1310720);
  tsplit_kernel<<<dim3(120, 40), 256, 0, stream>>>(w_qkv, wqt_hi, wqt_lo, 1280, 3840);
  tsplit_kernel<<<dim3(40, 40), 256, 0, stream>>>(w_proj, wpt_hi, wpt_lo, 1280, 1280);
  gemm_x3_kernel<<<dim3(60, 64), 256, 0, stream>>>(x_hi, x_lo, wqt_hi, wqt_lo,
                                                   b_qkv, qkv, 4096, 3840, 1280);
  rope_kernel<<<20480, 256, 0, stream>>>(qkv, cs, sn);
  attn_kernel<<<dim3(64, 16), 256, 0, stream>>>(qkv, cu, obuf);
  split_kernel<<<5120, 256, 0, stream>>>(obuf, o_hi, o_lo, 1310720);
  gemm_x3_kernel<<<dim3(20, 64), 256, 0, stream>>>(o_hi, o_lo, wpt_hi, wpt_lo,
                                                   b_proj, out, 4096, 1280, 1280);
}

// Round 3
// 562.307 us; speedup vs baseline: 1.5998x; 1.5998x over previous
//
#include <hip/hip_runtime.h>
#include <cstdint>
#include <cstddef>

typedef __bf16 bf16x8 __attribute__((ext_vector_type(8)));
typedef float f32x4 __attribute__((ext_vector_type(4)));

#define SEQ   4096
#define HID   1280
#define NH    16
#define HD    80
#define NQKV  3840

__device__ __forceinline__ unsigned short f2bf(float f) {
  unsigned int u = __float_as_uint(f);
  unsigned int r = u + 0x7FFFu + ((u >> 16) & 1u);   // RNE
  return (unsigned short)(r >> 16);
}
__device__ __forceinline__ float bf2f(unsigned short h) {
  return __uint_as_float(((unsigned int)h) << 16);
}
__device__ __forceinline__ __bf16 us2bf(unsigned short u) {
  union { unsigned short s; __bf16 b; } c; c.s = u; return c.b;
}
__device__ __forceinline__ void dma16(const void* g, void* l) {
  __builtin_amdgcn_global_load_lds((const __attribute__((address_space(1))) unsigned int*)g,
                                   (__attribute__((address_space(3))) unsigned int*)l, 16, 0, 0);
}

// ---------------- split: f32 -> bf16 hi + bf16 lo ----------------------------
__global__ __launch_bounds__(256) void split_kernel(const float* __restrict__ x,
                                                    unsigned short* __restrict__ hi,
                                                    unsigned short* __restrict__ lo,
                                                    int n4) {
  int i = blockIdx.x * 256 + threadIdx.x;
  if (i >= n4) return;
  float4 v = *((const float4*)x + i);
  float vv[4] = {v.x, v.y, v.z, v.w};
  unsigned short hh[4], ll[4];
#pragma unroll
  for (int j = 0; j < 4; ++j) {
    hh[j] = f2bf(vv[j]);
    ll[j] = f2bf(vv[j] - bf2f(hh[j]));
  }
  *((ushort4*)hi + i) = make_ushort4(hh[0], hh[1], hh[2], hh[3]);
  *((ushort4*)lo + i) = make_ushort4(ll[0], ll[1], ll[2], ll[3]);
}

// ---------------- transpose + split weights ---------------------------------
__global__ __launch_bounds__(256) void tsplit_kernel(const float* __restrict__ W,
                                                     unsigned short* __restrict__ Thi,
                                                     unsigned short* __restrict__ Tlo,
                                                     int K, int N) {
  __shared__ float tile[32][33];
  int n0 = blockIdx.x * 32, k0 = blockIdx.y * 32;
  int tx = threadIdx.x & 31, ty = threadIdx.x >> 5;
#pragma unroll
  for (int i = 0; i < 32; i += 8)
    tile[ty + i][tx] = W[(size_t)(k0 + ty + i) * N + n0 + tx];
  __syncthreads();
#pragma unroll
  for (int i = 0; i < 32; i += 8) {
    float v = tile[tx][ty + i];
    size_t idx = (size_t)(n0 + ty + i) * K + (size_t)(k0 + tx);
    unsigned short h = f2bf(v);
    Thi[idx] = h;
    Tlo[idx] = f2bf(v - bf2f(h));
  }
}

// ---------------- GEMM: C = A*B + bias, bf16x3 (fp32-accurate) ---------------
__global__ __launch_bounds__(256) void gemm_x3_kernel(
    const unsigned short* __restrict__ Ah, const unsigned short* __restrict__ Al,
    const unsigned short* __restrict__ Bh, const unsigned short* __restrict__ Bl,
    const float* __restrict__ bias, float* __restrict__ C,
    int M, int N, int K) {
  __shared__ __align__(16) unsigned short sAh[64][72];
  __shared__ __align__(16) unsigned short sAl[64][72];
  __shared__ __align__(16) unsigned short sBh[64][72];
  __shared__ __align__(16) unsigned short sBl[64][72];

  const int t = threadIdx.x;
  const int bm = blockIdx.y * 64, bn = blockIdx.x * 64;
  const int lane = t & 63, wave = t >> 6;
  const int wr = (wave >> 1) * 32, wc = (wave & 1) * 32;
  const int row16 = lane & 15, quad = lane >> 4;

  f32x4 acc[2][2];
#pragma unroll
  for (int i = 0; i < 2; ++i)
#pragma unroll
    for (int j = 0; j < 2; ++j) acc[i][j] = (f32x4){0.f, 0.f, 0.f, 0.f};

  const int r0 = t >> 3, c80 = (t & 7) * 8;
  const int r1 = (t + 256) >> 3;

  const unsigned short* pAh = Ah + (size_t)bm * K;
  const unsigned short* pAl = Al + (size_t)bm * K;
  const unsigned short* pBh = Bh + (size_t)bn * K;
  const unsigned short* pBl = Bl + (size_t)bn * K;

  for (int k0 = 0; k0 < K; k0 += 64) {
    __syncthreads();
    *(uint4*)&sAh[r0][c80] = *(const uint4*)(pAh + (size_t)r0 * K + k0 + c80);
    *(uint4*)&sAh[r1][c80] = *(const uint4*)(pAh + (size_t)r1 * K + k0 + c80);
    *(uint4*)&sAl[r0][c80] = *(const uint4*)(pAl + (size_t)r0 * K + k0 + c80);
    *(uint4*)&sAl[r1][c80] = *(const uint4*)(pAl + (size_t)r1 * K + k0 + c80);
    *(uint4*)&sBh[r0][c80] = *(const uint4*)(pBh + (size_t)r0 * K + k0 + c80);
    *(uint4*)&sBh[r1][c80] = *(const uint4*)(pBh + (size_t)r1 * K + k0 + c80);
    *(uint4*)&sBl[r0][c80] = *(const uint4*)(pBl + (size_t)r0 * K + k0 + c80);
    *(uint4*)&sBl[r1][c80] = *(const uint4*)(pBl + (size_t)r1 * K + k0 + c80);
    __syncthreads();
#pragma unroll
    for (int ks = 0; ks < 64; ks += 32) {
      bf16x8 ah[2], al[2], bh[2], bl[2];
#pragma unroll
      for (int mi = 0; mi < 2; ++mi) {
        ah[mi] = *(const bf16x8*)&sAh[wr + mi * 16 + row16][ks + quad * 8];
        al[mi] = *(const bf16x8*)&sAl[wr + mi * 16 + row16][ks + quad * 8];
      }
#pragma unroll
      for (int ni = 0; ni < 2; ++ni) {
        bh[ni] = *(const bf16x8*)&sBh[wc + ni * 16 + row16][ks + quad * 8];
        bl[ni] = *(const bf16x8*)&sBl[wc + ni * 16 + row16][ks + quad * 8];
      }
#pragma unroll
      for (int mi = 0; mi < 2; ++mi)
#pragma unroll
        for (int ni = 0; ni < 2; ++ni) {
          acc[mi][ni] = __builtin_amdgcn_mfma_f32_16x16x32_bf16(ah[mi], bh[ni], acc[mi][ni], 0, 0, 0);
          acc[mi][ni] = __builtin_amdgcn_mfma_f32_16x16x32_bf16(ah[mi], bl[ni], acc[mi][ni], 0, 0, 0);
          acc[mi][ni] = __builtin_amdgcn_mfma_f32_16x16x32_bf16(al[mi], bh[ni], acc[mi][ni], 0, 0, 0);
        }
    }
  }
#pragma unroll
  for (int mi = 0; mi < 2; ++mi)
#pragma unroll
    for (int ni = 0; ni < 2; ++ni) {
      int col = bn + wc + ni * 16 + row16;
      float bv = bias[col];
#pragma unroll
      for (int r = 0; r < 4; ++r) {
        int rowg = bm + wr + mi * 16 + quad * 4 + r;
        C[(size_t)rowg * N + col] = acc[mi][ni][r] + bv;
      }
    }
}

// ---------------- RoPE in-place on q and k parts of qkv ----------------------
__global__ __launch_bounds__(256) void rope_kernel(float* __restrict__ qkv,
                                                   const float* __restrict__ cs,
                                                   const float* __restrict__ sn) {
  int idx = blockIdx.x * 256 + threadIdx.x;  // < 4096*2*16*40
  int d = idx % 40;
  int rest = idx / 40;
  int h = rest % 16; rest /= 16;
  int qk = rest & 1;
  int s = rest >> 1;
  float* base = qkv + (size_t)s * NQKV + qk * HID + h * HD;
  float c0 = cs[s * HD + d],      s0 = sn[s * HD + d];
  float c1 = cs[s * HD + d + 40], s1 = sn[s * HD + d + 40];
  float x0 = base[d], x1 = base[d + 40];
  base[d]      = x0 * c0 - x1 * s0;
  base[d + 40] = x1 * c1 + x0 * s1;
}

// ---------------- pack roped K to bf16 hi/lo, head-major [h][s][80] ----------
__global__ __launch_bounds__(256) void pack_k_kernel(const float* __restrict__ qkv,
                                                     unsigned short* __restrict__ khi,
                                                     unsigned short* __restrict__ klo) {
  int h = blockIdx.y;
  int s = blockIdx.x * 64 + (threadIdx.x >> 2);
  int db = (threadIdx.x & 3) * 20;
  const float* src = qkv + (size_t)s * NQKV + HID + h * HD + db;
  unsigned short hh[20], ll[20];
#pragma unroll
  for (int i = 0; i < 5; ++i) {
    float4 v = *(const float4*)(src + 4 * i);
    float vv[4] = {v.x, v.y, v.z, v.w};
#pragma unroll
    for (int j = 0; j < 4; ++j) {
      unsigned short hu = f2bf(vv[j]);
      hh[i * 4 + j] = hu;
      ll[i * 4 + j] = f2bf(vv[j] - bf2f(hu));
    }
  }
  size_t dst = ((size_t)h * SEQ + s) * 80 + db;
#pragma unroll
  for (int i = 0; i < 5; ++i) {
    *(ushort4*)&khi[dst + 4 * i] = make_ushort4(hh[4 * i], hh[4 * i + 1], hh[4 * i + 2], hh[4 * i + 3]);
    *(ushort4*)&klo[dst + 4 * i] = make_ushort4(ll[4 * i], ll[4 * i + 1], ll[4 * i + 2], ll[4 * i + 3]);
  }
}

// ---------------- attention: MFMA bf16x3, register online-softmax ------------
// grid (64 q-tiles, 16 heads), 256 thr (4 waves x 16 q-rows each).
__global__ __launch_bounds__(256, 2) void attn_kernel(
    const float* __restrict__ qkv, const unsigned short* __restrict__ khi,
    const unsigned short* __restrict__ klo, const int* __restrict__ cu,
    float* __restrict__ o) {
  __shared__ __align__(16) unsigned short sKh[64][80];   // DMA-filled, contiguous
  __shared__ __align__(16) unsigned short sKl[64][80];
  __shared__ __align__(16) unsigned short sVh[80][72];   // V^T, padded rows
  __shared__ __align__(16) unsigned short sVl[80][72];
  __shared__ __align__(16) unsigned int   sP[64][68];    // packed ph | pl<<16
  __shared__ int segk[64], segq[64];
  __shared__ int cu_s[9];

  const int t = threadIdx.x;
  const int h = blockIdx.y;
  const int r0 = blockIdx.x * 64;
  const int lane = t & 63, wave = t >> 6;
  const int c16 = lane & 15, quad = lane >> 4;

  if (t < 9) cu_s[t] = cu[t];
  __syncthreads();
  if (t < 64) {
    int pos = r0 + t, sg = 0;
#pragma unroll
    for (int i = 1; i < 8; ++i) sg += (pos >= cu_s[i]) ? 1 : 0;
    segq[t] = sg;
  }
  __syncthreads();
  const int kstart = cu_s[segq[0]];
  const int kend   = cu_s[segq[63] + 1];
  int sq[4];
#pragma unroll
  for (int r = 0; r < 4; ++r) sq[r] = segq[wave * 16 + quad * 4 + r];

  // Q fragments in registers, scale folded in
  const float scale = 0.11180339887498949f;  // 80^-0.5
  bf16x8 qh[3], ql[3];
  {
    const float* qrow = qkv + (size_t)(r0 + wave * 16 + c16) * NQKV + h * HD;
#pragma unroll
    for (int ks = 0; ks < 3; ++ks) {
      int d = ks * 32 + quad * 8;
      bf16x8 hf = {}, lf = {};
      if (d < 80) {
#pragma unroll
        for (int j = 0; j < 8; ++j) {
          float v = qrow[d + j] * scale;
          unsigned short hu = f2bf(v);
          hf[j] = us2bf(hu);
          lf[j] = us2bf(f2bf(v - bf2f(hu)));
        }
      }
      qh[ks] = hf; ql[ks] = lf;
    }
  }

  f32x4 O[5];
#pragma unroll
  for (int dt = 0; dt < 5; ++dt) O[dt] = (f32x4){0.f, 0.f, 0.f, 0.f};
  float mrow[4] = {-1e30f, -1e30f, -1e30f, -1e30f};
  float lrow[4] = {0.f, 0.f, 0.f, 0.f};

  const size_t KARR = (size_t)NH * SEQ * 80 * 2;  // bytes per packed array

  for (int ck = kstart; ck < kend; ck += 64) {
    __syncthreads();
    // --- K chunk via global_load_lds DMA (5 x 1KB units per wave) ---
    {
      size_t chunk_off = ((size_t)h * SEQ + ck) * 80;  // elements
#pragma unroll
      for (int i = 0; i < 5; ++i) {
        int u = wave * 5 + i;
        int isHi = (u < 10);
        int uu = isHi ? u : u - 10;
        const unsigned short* garr = isHi ? khi : klo;
        const char* g = (const char*)(garr + chunk_off) + uu * 1024 + lane * 16;
        const char* glim = (const char*)garr + KARR - 16;
        if (g > glim) g = glim;  // clamp OOB tail (masked later)
        unsigned short* l = (isHi ? &sKh[0][0] : &sKl[0][0]) + uu * 512;
        dma16(g, l);
      }
    }
    // --- V chunk: convert f32 -> bf16 hi/lo, transpose into V^T ---
    {
      int row = t >> 2, db = (t & 3) * 20;
      int tr = ck + row; if (tr > SEQ - 1) tr = SEQ - 1;
      const float* src = qkv + (size_t)tr * NQKV + 2 * HID + h * HD + db;
#pragma unroll
      for (int i2 = 0; i2 < 5; ++i2) {
        float4 v = *(const float4*)(src + 4 * i2);
        float vv[4] = {v.x, v.y, v.z, v.w};
#pragma unroll
        for (int j = 0; j < 4; ++j) {
          int d = db + i2 * 4 + j;
          unsigned short hu = f2bf(vv[j]);
          sVh[d][row] = hu;
          sVl[d][row] = f2bf(vv[j] - bf2f(hu));
        }
      }
    }
    if (t < 64) {
      int tk = ck + t, sg = -1;
      if (tk < kend) {
        sg = 0;
#pragma unroll
        for (int i = 1; i < 8; ++i) sg += (tk >= cu_s[i]) ? 1 : 0;
      }
      segk[t] = sg;
    }
    __syncthreads();

    // --- QK^T: 4 n-tiles x 3 k-steps x 3 terms ---
    f32x4 sc[4];
#pragma unroll
    for (int nt = 0; nt < 4; ++nt) sc[nt] = (f32x4){0.f, 0.f, 0.f, 0.f};
#pragma unroll
    for (int nt = 0; nt < 4; ++nt) {
      int krow = nt * 16 + c16;
#pragma unroll
      for (int ks = 0; ks < 3; ++ks) {
        int d = ks * 32 + quad * 8;
        bf16x8 kh = {}, kl = {};
        if (d < 80) {
          kh = *(const bf16x8*)&sKh[krow][d];
          kl = *(const bf16x8*)&sKl[krow][d];
        }
        sc[nt] = __builtin_amdgcn_mfma_f32_16x16x32_bf16(qh[ks], kh, sc[nt], 0, 0, 0);
        sc[nt] = __builtin_amdgcn_mfma_f32_16x16x32_bf16(qh[ks], kl, sc[nt], 0, 0, 0);
        sc[nt] = __builtin_amdgcn_mfma_f32_16x16x32_bf16(ql[ks], kh, sc[nt], 0, 0, 0);
      }
    }

    // --- mask + online softmax in registers (C layout: col=c16, row=quad*4+r)
    int sk[4];
#pragma unroll
    for (int nt = 0; nt < 4; ++nt) sk[nt] = segk[nt * 16 + c16];
    float alpha[4];
#pragma unroll
    for (int r = 0; r < 4; ++r) {
      float mx = -1e30f;
#pragma unroll
      for (int nt = 0; nt < 4; ++nt) {
        float v = (sk[nt] == sq[r]) ? sc[nt][r] : -1e30f;
        mx = fmaxf(mx, v);
      }
      mx = fmaxf(mx, __shfl_xor(mx, 1));
      mx = fmaxf(mx, __shfl_xor(mx, 2));
      mx = fmaxf(mx, __shfl_xor(mx, 4));
      mx = fmaxf(mx, __shfl_xor(mx, 8));
      float mnew = fmaxf(mrow[r], mx);
      alpha[r] = __expf(mrow[r] - mnew);
      float ps = 0.f;
#pragma unroll
      for (int nt = 0; nt < 4; ++nt) {
        float p = (sk[nt] == sq[r]) ? __expf(sc[nt][r] - mnew) : 0.f;
        ps += p;
        unsigned short ph = f2bf(p);
        unsigned short pl = f2bf(p - bf2f(ph));
        sP[wave * 16 + quad * 4 + r][nt * 16 + c16] = (unsigned)ph | ((unsigned)pl << 16);
      }
      ps += __shfl_xor(ps, 1);
      ps += __shfl_xor(ps, 2);
      ps += __shfl_xor(ps, 4);
      ps += __shfl_xor(ps, 8);
      lrow[r] = lrow[r] * alpha[r] + ps;
      mrow[r] = mnew;
    }
#pragma unroll
    for (int dt = 0; dt < 5; ++dt) {
      f32x4 ov = O[dt];
      ov[0] *= alpha[0]; ov[1] *= alpha[1]; ov[2] *= alpha[2]; ov[3] *= alpha[3];
      O[dt] = ov;
    }
    __syncthreads();

    // --- PV: A = P (row-major, unpacked via v_perm), B = V^T rows ---
#pragma unroll
    for (int ks = 0; ks < 2; ++ks) {
      uint4 w0 = *(const uint4*)&sP[wave * 16 + c16][ks * 32 + quad * 8];
      uint4 w1 = *(const uint4*)&sP[wave * 16 + c16][ks * 32 + quad * 8 + 4];
      union { unsigned int u[4]; bf16x8 v; } ph, pl;
      ph.u[0] = __builtin_amdgcn_perm(w0.y, w0.x, 0x05040100u);
      ph.u[1] = __builtin_amdgcn_perm(w0.w, w0.z, 0x05040100u);
      ph.u[2] = __builtin_amdgcn_perm(w1.y, w1.x, 0x05040100u);
      ph.u[3] = __builtin_amdgcn_perm(w1.w, w1.z, 0x05040100u);
      pl.u[0] = __builtin_amdgcn_perm(w0.y, w0.x, 0x07060302u);
      pl.u[1] = __builtin_amdgcn_perm(w0.w, w0.z, 0x07060302u);
      pl.u[2] = __builtin_amdgcn_perm(w1.y, w1.x, 0x07060302u);
      pl.u[3] = __builtin_amdgcn_perm(w1.w, w1.z, 0x07060302u);
#pragma unroll
      for (int dt = 0; dt < 5; ++dt) {
        bf16x8 vh = *(const bf16x8*)&sVh[dt * 16 + c16][ks * 32 + quad * 8];
        bf16x8 vl = *(const bf16x8*)&sVl[dt * 16 + c16][ks * 32 + quad * 8];
        O[dt] = __builtin_amdgcn_mfma_f32_16x16x32_bf16(ph.v, vh, O[dt], 0, 0, 0);
        O[dt] = __builtin_amdgcn_mfma_f32_16x16x32_bf16(ph.v, vl, O[dt], 0, 0, 0);
        O[dt] = __builtin_amdgcn_mfma_f32_16x16x32_bf16(pl.v, vh, O[dt], 0, 0, 0);
      }
    }
  }

  float inv[4];
#pragma unroll
  for (int r = 0; r < 4; ++r) inv[r] = 1.0f / lrow[r];
#pragma unroll
  for (int dt = 0; dt < 5; ++dt)
#pragma unroll
    for (int r = 0; r < 4; ++r) {
      int rowg = r0 + wave * 16 + quad * 4 + r;
      o[(size_t)rowg * HID + h * HD + dt * 16 + c16] = O[dt][r] * inv[r];
    }
}

// ---------------- host launcher ---------------------------------------------
extern "C" void kernel_launch(void* const* d_in, const int* in_sizes, int n_in,
                              void* d_out, int out_size, void* d_ws, size_t ws_size,
                              hipStream_t stream) {
  const float* x      = (const float*)d_in[0];
  const int*   cu     = (const int*)d_in[1];
  const float* cs     = (const float*)d_in[2];
  const float* sn     = (const float*)d_in[3];
  const float* w_qkv  = (const float*)d_in[4];
  const float* b_qkv  = (const float*)d_in[5];
  const float* w_proj = (const float*)d_in[6];
  const float* b_proj = (const float*)d_in[7];
  float* out = (float*)d_out;

  char* ws = (char*)d_ws;
  // layout (bytes), with lifetime-based overlays:
  //   [0, 62914560)            qkv f32 (gemm1 out; q-part read by attn)
  //   [62914560, 83886080)     x_hi/x_lo  ->  khi/klo  ->  o_hi/o_lo
  //   [83886080, 90439680)     wprojT hi/lo (live until gemm2)
  //   [90439680, 110100480)    wqkvT hi/lo (dead after gemm1) -> obuf f32
  float*          qkv    = (float*)(ws + 0);
  unsigned short* x_hi   = (unsigned short*)(ws + 62914560ULL);
  unsigned short* x_lo   = (unsigned short*)(ws + 73400320ULL);
  unsigned short* khi    = (unsigned short*)(ws + 62914560ULL);
  unsigned short* klo    = (unsigned short*)(ws + 73400320ULL);
  unsigned short* o_hi   = (unsigned short*)(ws + 62914560ULL);
  unsigned short* o_lo   = (unsigned short*)(ws + 73400320ULL);
  unsigned short* wpt_hi = (unsigned short*)(ws + 83886080ULL);
  unsigned short* wpt_lo = (unsigned short*)(ws + 87162880ULL);
  unsigned short* wqt_hi = (unsigned short*)(ws + 90439680ULL);
  unsigned short* wqt_lo = (unsigned short*)(ws + 100270080ULL);
  float*          obuf   = (float*)(ws + 90439680ULL);

  split_kernel<<<5120, 256, 0, stream>>>(x, x_hi, x_lo, 1310720);
  tsplit_kernel<<<dim3(120, 40), 256, 0, stream>>>(w_qkv, wqt_hi, wqt_lo, 1280, 3840);
  tsplit_kernel<<<dim3(40, 40), 256, 0, stream>>>(w_proj, wpt_hi, wpt_lo, 1280, 1280);
  gemm_x3_kernel<<<dim3(60, 64), 256, 0, stream>>>(x_hi, x_lo, wqt_hi, wqt_lo,
                                                   b_qkv, qkv, 4096, 3840, 1280);
  rope_kernel<<<20480, 256, 0, stream>>>(qkv, cs, sn);
  pack_k_kernel<<<dim3(64, 16), 256, 0, stream>>>(qkv, khi, klo);
  attn_kernel<<<dim3(64, 16), 256, 0, stream>>>(qkv, khi, klo, cu, obuf);
  split_kernel<<<5120, 256, 0, stream>>>(obuf, o_hi, o_lo, 1310720);
  gemm_x3_kernel<<<dim3(20, 64), 256, 0, stream>>>(o_hi, o_lo, wpt_hi, wpt_lo,
                                                   b_proj, out, 4096, 1280, 1280);
}

// Round 4
// 457.242 us; speedup vs baseline: 1.9674x; 1.2298x over previous
//
#include <hip/hip_runtime.h>
#include <cstdint>
#include <cstddef>

typedef __bf16 bf16x8 __attribute__((ext_vector_type(8)));
typedef float f32x4 __attribute__((ext_vector_type(4)));

#define SEQ   4096
#define HID   1280
#define NH    16
#define HD    80

__device__ __forceinline__ unsigned short f2bf(float f) {
  unsigned int u = __float_as_uint(f);
  unsigned int r = u + 0x7FFFu + ((u >> 16) & 1u);   // RNE
  return (unsigned short)(r >> 16);
}
__device__ __forceinline__ float bf2f(unsigned short h) {
  return __uint_as_float(((unsigned int)h) << 16);
}
__device__ __forceinline__ __bf16 us2bf(unsigned short u) {
  union { unsigned short s; __bf16 b; } c; c.s = u; return c.b;
}
__device__ __forceinline__ void dma16(const void* g, void* l) {
  __builtin_amdgcn_global_load_lds((const __attribute__((address_space(1))) unsigned int*)g,
                                   (__attribute__((address_space(3))) unsigned int*)l, 16, 0, 0);
}

// ---------------- split: f32 -> bf16 hi + bf16 lo ----------------------------
__global__ __launch_bounds__(256) void split_kernel(const float* __restrict__ x,
                                                    unsigned short* __restrict__ hi,
                                                    unsigned short* __restrict__ lo,
                                                    int n4) {
  int i = blockIdx.x * 256 + threadIdx.x;
  if (i >= n4) return;
  float4 v = *((const float4*)x + i);
  float vv[4] = {v.x, v.y, v.z, v.w};
  unsigned short hh[4], ll[4];
#pragma unroll
  for (int j = 0; j < 4; ++j) {
    hh[j] = f2bf(vv[j]);
    ll[j] = f2bf(vv[j] - bf2f(hh[j]));
  }
  *((ushort4*)hi + i) = make_ushort4(hh[0], hh[1], hh[2], hh[3]);
  *((ushort4*)lo + i) = make_ushort4(ll[0], ll[1], ll[2], ll[3]);
}

// ---------------- transpose + split weights ---------------------------------
__global__ __launch_bounds__(256) void tsplit_kernel(const float* __restrict__ W,
                                                     unsigned short* __restrict__ Thi,
                                                     unsigned short* __restrict__ Tlo,
                                                     int K, int N) {
  __shared__ float tile[32][33];
  int n0 = blockIdx.x * 32, k0 = blockIdx.y * 32;
  int tx = threadIdx.x & 31, ty = threadIdx.x >> 5;
#pragma unroll
  for (int i = 0; i < 32; i += 8)
    tile[ty + i][tx] = W[(size_t)(k0 + ty + i) * N + n0 + tx];
  __syncthreads();
#pragma unroll
  for (int i = 0; i < 32; i += 8) {
    float v = tile[tx][ty + i];
    size_t idx = (size_t)(n0 + ty + i) * K + (size_t)(k0 + tx);
    unsigned short h = f2bf(v);
    Thi[idx] = h;
    Tlo[idx] = f2bf(v - bf2f(h));
  }
}

// ---------------- 128x128 DMA GEMM, bf16x3 (fp32-accurate) -------------------
// A: M x K bf16 hi/lo row-major. B: N x K bf16 hi/lo (W^T). Output f32 split
// into up to three 1280-col planes (ld 1280 each), + bias.
__global__ __launch_bounds__(256, 2) void gemm128_x3(
    const unsigned short* __restrict__ Ah, const unsigned short* __restrict__ Al,
    const unsigned short* __restrict__ Bh, const unsigned short* __restrict__ Bl,
    const float* __restrict__ bias,
    float* __restrict__ out0, float* __restrict__ out1, float* __restrict__ out2,
    int M, int N, int K) {
  // 4 tiles of [128][64] shorts = 16 KB each: 0=Ah 1=Al 2=Bh 3=Bl
  __shared__ __align__(16) unsigned short sT[4][8192];

  const int t = threadIdx.x;
  const int lane = t & 63, wave = t >> 6;
  const int c16 = lane & 15, quad = lane >> 4;
  const int bm = blockIdx.y * 128, bn = blockIdx.x * 128;
  const int wr = (wave >> 1) * 64, wc = (wave & 1) * 64;

  f32x4 acc[4][4];
#pragma unroll
  for (int i = 0; i < 4; ++i)
#pragma unroll
    for (int j = 0; j < 4; ++j) acc[i][j] = (f32x4){0.f, 0.f, 0.f, 0.f};

  // DMA lane invariants
  const int lrow = lane >> 3;               // 0..7
  const int lswz = (lane & 7) ^ lrow;       // read-side swizzled k-group
  const unsigned short* garr = (wave == 0) ? Ah : (wave == 1) ? Al
                               : (wave == 2) ? Bh : Bl;
  const int gbase_row = (wave < 2) ? bm : bn;
  unsigned short* larr = &sT[wave][0];

  for (int k0 = 0; k0 < K; k0 += 64) {
    __syncthreads();
#pragma unroll
    for (int i = 0; i < 16; ++i) {
      const unsigned short* g = garr + (size_t)(gbase_row + 8 * i + lrow) * K
                                + k0 + lswz * 8;
      dma16(g, larr + i * 512);
    }
    __syncthreads();
#pragma unroll
    for (int ks = 0; ks < 2; ++ks) {
      const int aswz = ((ks * 4 + quad) ^ (c16 & 7)) * 8;
      bf16x8 a[4][2], b[4][2];
#pragma unroll
      for (int mi = 0; mi < 4; ++mi) {
        int row = wr + mi * 16 + c16;
        a[mi][0] = *(const bf16x8*)&sT[0][row * 64 + aswz];
        a[mi][1] = *(const bf16x8*)&sT[1][row * 64 + aswz];
      }
#pragma unroll
      for (int ni = 0; ni < 4; ++ni) {
        int row = wc + ni * 16 + c16;
        b[ni][0] = *(const bf16x8*)&sT[2][row * 64 + aswz];
        b[ni][1] = *(const bf16x8*)&sT[3][row * 64 + aswz];
      }
#pragma unroll
      for (int mi = 0; mi < 4; ++mi)
#pragma unroll
        for (int ni = 0; ni < 4; ++ni) {
          acc[mi][ni] = __builtin_amdgcn_mfma_f32_16x16x32_bf16(a[mi][0], b[ni][0], acc[mi][ni], 0, 0, 0);
          acc[mi][ni] = __builtin_amdgcn_mfma_f32_16x16x32_bf16(a[mi][0], b[ni][1], acc[mi][ni], 0, 0, 0);
          acc[mi][ni] = __builtin_amdgcn_mfma_f32_16x16x32_bf16(a[mi][1], b[ni][0], acc[mi][ni], 0, 0, 0);
        }
    }
  }
  // epilogue: C/D layout col=c16, row=quad*4+r
#pragma unroll
  for (int ni = 0; ni < 4; ++ni) {
    int colg = bn + wc + ni * 16 + c16;
    float bv = bias[colg];
    float* op;
    int c = colg;
    if (c < 1280) op = out0;
    else if (c < 2560) { op = out1; c -= 1280; }
    else { op = out2; c -= 2560; }
#pragma unroll
    for (int mi = 0; mi < 4; ++mi) {
#pragma unroll
      for (int r = 0; r < 4; ++r) {
        int rowg = bm + wr + mi * 16 + quad * 4 + r;
        op[(size_t)rowg * 1280 + c] = acc[mi][ni][r] + bv;
      }
    }
  }
}

// ---------------- RoPE on q (in place, f32) + k -> packed bf16 hi/lo ---------
// grid (64 s-tiles, 16 heads), 256 thr: thread = (s = 4 per block? no: s=t>>2, 10 pairs)
__global__ __launch_bounds__(256) void rope_pack_kernel(
    float* __restrict__ qf, const float* __restrict__ kf,
    const float* __restrict__ cs, const float* __restrict__ sn,
    unsigned short* __restrict__ khi, unsigned short* __restrict__ klo) {
  const int h = blockIdx.y;
  const int s = blockIdx.x * 64 + (threadIdx.x >> 2);
  const int p = threadIdx.x & 3;
  float* qrow = qf + (size_t)s * HID + h * HD;
  const float* krow = kf + (size_t)s * HID + h * HD;
  const float* cr = cs + (size_t)s * HD;
  const float* sr = sn + (size_t)s * HD;
  unsigned short* kh = khi + ((size_t)h * SEQ + s) * HD;
  unsigned short* kl = klo + ((size_t)h * SEQ + s) * HD;
#pragma unroll
  for (int j = 0; j < 10; ++j) {
    int d = 10 * p + j;           // 0..39
    float c0 = cr[d], s0 = sr[d], c1 = cr[d + 40], s1 = sr[d + 40];
    float q0 = qrow[d], q1 = qrow[d + 40];
    qrow[d]      = q0 * c0 - q1 * s0;
    qrow[d + 40] = q1 * c1 + q0 * s1;
    float k0 = krow[d], k1 = krow[d + 40];
    float kn0 = k0 * c0 - k1 * s0;
    float kn1 = k1 * c1 + k0 * s1;
    unsigned short h0 = f2bf(kn0), h1 = f2bf(kn1);
    kh[d] = h0;      kl[d] = f2bf(kn0 - bf2f(h0));
    kh[d + 40] = h1; kl[d + 40] = f2bf(kn1 - bf2f(h1));
  }
}

// ---------------- pack V^T: f32 [s][1280] -> bf16 hi/lo [h][80][4096] --------
__global__ __launch_bounds__(256) void vt_pack_kernel(const float* __restrict__ vf,
                                                      unsigned short* __restrict__ vthi,
                                                      unsigned short* __restrict__ vtlo) {
  __shared__ unsigned short sTh[80][72];
  __shared__ unsigned short sTl[80][72];
  const int h = blockIdx.y;
  const int s0 = blockIdx.x * 64;
  const int t = threadIdx.x;
  {
    int row = t >> 2, p = (t & 3) * 20;
    const float* src = vf + (size_t)(s0 + row) * HID + h * HD + p;
#pragma unroll
    for (int i = 0; i < 5; ++i) {
      float4 v = *(const float4*)(src + 4 * i);
      float vv[4] = {v.x, v.y, v.z, v.w};
#pragma unroll
      for (int j = 0; j < 4; ++j) {
        int d = p + 4 * i + j;
        unsigned short hu = f2bf(vv[j]);
        sTh[d][row] = hu;
        sTl[d][row] = f2bf(vv[j] - bf2f(hu));
      }
    }
  }
  __syncthreads();
  if (t < 160) {
    int d = t >> 1, half = (t & 1) * 32;
    size_t base = (size_t)(h * HD + d) * SEQ + s0 + half;
#pragma unroll
    for (int i = 0; i < 8; ++i) {
      *(ushort4*)&vthi[base + 4 * i] = *(ushort4*)&sTh[d][half + 4 * i];
      *(ushort4*)&vtlo[base + 4 * i] = *(ushort4*)&sTl[d][half + 4 * i];
    }
  }
}

// ---------------- attention: MFMA bf16x3, all-DMA staging --------------------
// grid (16 heads, 64 q-tiles) -> head-major for XCD L2 affinity.
__global__ __launch_bounds__(256, 2) void attn_kernel(
    const float* __restrict__ qf, const unsigned short* __restrict__ khi,
    const unsigned short* __restrict__ klo, const unsigned short* __restrict__ vthi,
    const unsigned short* __restrict__ vtlo, const int* __restrict__ cu,
    unsigned short* __restrict__ ohi, unsigned short* __restrict__ olo) {
  __shared__ __align__(16) unsigned short sKh[64 * 80];
  __shared__ __align__(16) unsigned short sKl[64 * 80];
  __shared__ __align__(16) unsigned short sVh[80 * 64];   // V^T, swizzled groups
  __shared__ __align__(16) unsigned short sVl[80 * 64];
  __shared__ __align__(16) unsigned int   sP[64][68];     // packed ph | pl<<16
  __shared__ int segk[64], segq[64];
  __shared__ int cu_s[9];

  const int t = threadIdx.x;
  const int h = blockIdx.x;
  const int r0 = blockIdx.y * 64;
  const int lane = t & 63, wave = t >> 6;
  const int c16 = lane & 15, quad = lane >> 4;

  if (t < 9) cu_s[t] = cu[t];
  __syncthreads();
  if (t < 64) {
    int pos = r0 + t, sg = 0;
#pragma unroll
    for (int i = 1; i < 8; ++i) sg += (pos >= cu_s[i]) ? 1 : 0;
    segq[t] = sg;
  }
  __syncthreads();
  const int kstart = cu_s[segq[0]];
  const int kend   = cu_s[segq[63] + 1];
  const int ck0    = kstart & ~63;
  int sq[4];
#pragma unroll
  for (int r = 0; r < 4; ++r) sq[r] = segq[wave * 16 + quad * 4 + r];

  // Q fragments in registers, scale folded in
  const float scale = 0.11180339887498949f;  // 80^-0.5
  bf16x8 qh[3], ql[3];
  {
    const float* qrow = qf + (size_t)(r0 + wave * 16 + c16) * HID + h * HD;
#pragma unroll
    for (int ks = 0; ks < 3; ++ks) {
      int d = ks * 32 + quad * 8;
      bf16x8 hf = {}, lf = {};
      if (d < 80) {
        float4 v0 = *(const float4*)(qrow + d);
        float4 v1 = *(const float4*)(qrow + d + 4);
        float vv[8] = {v0.x, v0.y, v0.z, v0.w, v1.x, v1.y, v1.z, v1.w};
#pragma unroll
        for (int j = 0; j < 8; ++j) {
          float v = vv[j] * scale;
          unsigned short hu = f2bf(v);
          hf[j] = us2bf(hu);
          lf[j] = us2bf(f2bf(v - bf2f(hu)));
        }
      }
      qh[ks] = hf; ql[ks] = lf;
    }
  }

  f32x4 O[5];
#pragma unroll
  for (int dt = 0; dt < 5; ++dt) O[dt] = (f32x4){0.f, 0.f, 0.f, 0.f};
  float mrow[4] = {-1e30f, -1e30f, -1e30f, -1e30f};
  float lrow[4] = {0.f, 0.f, 0.f, 0.f};

  const int lr8 = lane >> 3;                 // DMA row-within-unit for V
  const int vswz_dma = (lane & 7) ^ lr8;     // read-side swizzle at DMA

  for (int ck = ck0; ck < kend; ck += 64) {
    __syncthreads();
    // --- stage K and V^T chunks purely via DMA: 10 units per wave ---
    if (wave < 2) {
      const unsigned short* garr = wave ? klo : khi;
      unsigned short* larr = wave ? sKl : sKh;
      size_t base = ((size_t)h * SEQ + ck) * 80;
#pragma unroll
      for (int i = 0; i < 10; ++i)
        dma16(garr + base + i * 512 + lane * 8, larr + i * 512);
    } else {
      const unsigned short* garr = (wave == 3) ? vtlo : vthi;
      unsigned short* larr = (wave == 3) ? sVl : sVh;
#pragma unroll
      for (int i = 0; i < 10; ++i)
        dma16(garr + (size_t)(h * HD + 8 * i + lr8) * SEQ + ck + vswz_dma * 8,
              larr + i * 512);
    }
    if (t < 64) {
      int tk = ck + t, sg = -1;
      if (tk < kend) {
        sg = 0;
#pragma unroll
        for (int i = 1; i < 8; ++i) sg += (tk >= cu_s[i]) ? 1 : 0;
      }
      segk[t] = sg;
    }
    __syncthreads();

    // --- QK^T: 4 n-tiles x 3 k-steps x 3 terms ---
    f32x4 sc[4];
#pragma unroll
    for (int nt = 0; nt < 4; ++nt) sc[nt] = (f32x4){0.f, 0.f, 0.f, 0.f};
#pragma unroll
    for (int nt = 0; nt < 4; ++nt) {
      int krow = nt * 16 + c16;
#pragma unroll
      for (int ks = 0; ks < 3; ++ks) {
        int d = ks * 32 + quad * 8;
        bf16x8 kh = {}, kl = {};
        if (d < 80) {
          kh = *(const bf16x8*)&sKh[krow * 80 + d];
          kl = *(const bf16x8*)&sKl[krow * 80 + d];
        }
        sc[nt] = __builtin_amdgcn_mfma_f32_16x16x32_bf16(qh[ks], kh, sc[nt], 0, 0, 0);
        sc[nt] = __builtin_amdgcn_mfma_f32_16x16x32_bf16(qh[ks], kl, sc[nt], 0, 0, 0);
        sc[nt] = __builtin_amdgcn_mfma_f32_16x16x32_bf16(ql[ks], kh, sc[nt], 0, 0, 0);
      }
    }

    // --- mask + online softmax in registers (C layout: col=c16=key, row=quad*4+r)
    int sk[4];
#pragma unroll
    for (int nt = 0; nt < 4; ++nt) sk[nt] = segk[nt * 16 + c16];
    float alpha[4];
#pragma unroll
    for (int r = 0; r < 4; ++r) {
      float mx = -1e30f;
#pragma unroll
      for (int nt = 0; nt < 4; ++nt) {
        float v = (sk[nt] == sq[r]) ? sc[nt][r] : -1e30f;
        mx = fmaxf(mx, v);
      }
      mx = fmaxf(mx, __shfl_xor(mx, 1));
      mx = fmaxf(mx, __shfl_xor(mx, 2));
      mx = fmaxf(mx, __shfl_xor(mx, 4));
      mx = fmaxf(mx, __shfl_xor(mx, 8));
      float mnew = fmaxf(mrow[r], mx);
      alpha[r] = __expf(mrow[r] - mnew);
      float ps = 0.f;
#pragma unroll
      for (int nt = 0; nt < 4; ++nt) {
        float p = (sk[nt] == sq[r]) ? __expf(sc[nt][r] - mnew) : 0.f;
        ps += p;
        unsigned short ph = f2bf(p);
        unsigned short pl = f2bf(p - bf2f(ph));
        sP[wave * 16 + quad * 4 + r][nt * 16 + c16] = (unsigned)ph | ((unsigned)pl << 16);
      }
      ps += __shfl_xor(ps, 1);
      ps += __shfl_xor(ps, 2);
      ps += __shfl_xor(ps, 4);
      ps += __shfl_xor(ps, 8);
      lrow[r] = lrow[r] * alpha[r] + ps;
      mrow[r] = mnew;
    }
#pragma unroll
    for (int dt = 0; dt < 5; ++dt) {
      f32x4 ov = O[dt];
      ov[0] *= alpha[0]; ov[1] *= alpha[1]; ov[2] *= alpha[2]; ov[3] *= alpha[3];
      O[dt] = ov;
    }
    __syncthreads();

    // --- PV: A = P (unpacked via v_perm), B = V^T rows (swizzled groups) ---
#pragma unroll
    for (int ks = 0; ks < 2; ++ks) {
      uint4 w0 = *(const uint4*)&sP[wave * 16 + c16][ks * 32 + quad * 8];
      uint4 w1 = *(const uint4*)&sP[wave * 16 + c16][ks * 32 + quad * 8 + 4];
      union { unsigned int u[4]; bf16x8 v; } ph, pl;
      ph.u[0] = __builtin_amdgcn_perm(w0.y, w0.x, 0x05040100u);
      ph.u[1] = __builtin_amdgcn_perm(w0.w, w0.z, 0x05040100u);
      ph.u[2] = __builtin_amdgcn_perm(w1.y, w1.x, 0x05040100u);
      ph.u[3] = __builtin_amdgcn_perm(w1.w, w1.z, 0x05040100u);
      pl.u[0] = __builtin_amdgcn_perm(w0.y, w0.x, 0x07060302u);
      pl.u[1] = __builtin_amdgcn_perm(w0.w, w0.z, 0x07060302u);
      pl.u[2] = __builtin_amdgcn_perm(w1.y, w1.x, 0x07060302u);
      pl.u[3] = __builtin_amdgcn_perm(w1.w, w1.z, 0x07060302u);
      const int g = ks * 4 + quad;
#pragma unroll
      for (int dt = 0; dt < 5; ++dt) {
        int d = dt * 16 + c16;
        int off = d * 64 + ((g ^ (d & 7)) * 8);
        bf16x8 vh = *(const bf16x8*)&sVh[off];
        bf16x8 vl = *(const bf16x8*)&sVl[off];
        O[dt] = __builtin_amdgcn_mfma_f32_16x16x32_bf16(ph.v, vh, O[dt], 0, 0, 0);
        O[dt] = __builtin_amdgcn_mfma_f32_16x16x32_bf16(ph.v, vl, O[dt], 0, 0, 0);
        O[dt] = __builtin_amdgcn_mfma_f32_16x16x32_bf16(pl.v, vh, O[dt], 0, 0, 0);
      }
    }
  }

  float inv[4];
#pragma unroll
  for (int r = 0; r < 4; ++r) inv[r] = 1.0f / lrow[r];
#pragma unroll
  for (int dt = 0; dt < 5; ++dt)
#pragma unroll
    for (int r = 0; r < 4; ++r) {
      int rowg = r0 + wave * 16 + quad * 4 + r;
      float val = O[dt][r] * inv[r];
      unsigned short hu = f2bf(val);
      size_t idx = (size_t)rowg * HID + h * HD + dt * 16 + c16;
      ohi[idx] = hu;
      olo[idx] = f2bf(val - bf2f(hu));
    }
}

// ---------------- host launcher ---------------------------------------------
extern "C" void kernel_launch(void* const* d_in, const int* in_sizes, int n_in,
                              void* d_out, int out_size, void* d_ws, size_t ws_size,
                              hipStream_t stream) {
  const float* x      = (const float*)d_in[0];
  const int*   cu     = (const int*)d_in[1];
  const float* cs     = (const float*)d_in[2];
  const float* sn     = (const float*)d_in[3];
  const float* w_qkv  = (const float*)d_in[4];
  const float* b_qkv  = (const float*)d_in[5];
  const float* w_proj = (const float*)d_in[6];
  const float* b_proj = (const float*)d_in[7];
  float* out = (float*)d_out;

  char* ws = (char*)d_ws;
  // layout (bytes), lifetime overlays:
  //  [0,        20.97M)  qf f32                     (gemm1 -> attn)
  //  [20.97M,   41.94M)  kf f32      -> o_hi/o_lo   (rope_pack / attn out)
  //  [41.94M,   62.91M)  vf f32      -> wpt hi/lo   (vt_pack / gemm2)
  //  [62.91M,   83.89M)  x hi/lo     -> khi/klo
  //  [83.89M,  104.86M)  wqt hi/lo   -> vthi/vtlo
  float*          qf     = (float*)(ws + 0);
  float*          kf     = (float*)(ws + 20971520ULL);
  float*          vf     = (float*)(ws + 41943040ULL);
  unsigned short* o_hi   = (unsigned short*)(ws + 20971520ULL);
  unsigned short* o_lo   = (unsigned short*)(ws + 31457280ULL);
  unsigned short* wpt_hi = (unsigned short*)(ws + 41943040ULL);
  unsigned short* wpt_lo = (unsigned short*)(ws + 45219840ULL);
  unsigned short* x_hi   = (unsigned short*)(ws + 62914560ULL);
  unsigned short* x_lo   = (unsigned short*)(ws + 73400320ULL);
  unsigned short* khi    = (unsigned short*)(ws + 62914560ULL);
  unsigned short* klo    = (unsigned short*)(ws + 73400320ULL);
  unsigned short* wqt_hi = (unsigned short*)(ws + 83886080ULL);
  unsigned short* wqt_lo = (unsigned short*)(ws + 93716480ULL);
  unsigned short* vthi   = (unsigned short*)(ws + 83886080ULL);
  unsigned short* vtlo   = (unsigned short*)(ws + 94371840ULL);

  split_kernel<<<5120, 256, 0, stream>>>(x, x_hi, x_lo, 1310720);
  tsplit_kernel<<<dim3(120, 40), 256, 0, stream>>>(w_qkv, wqt_hi, wqt_lo, 1280, 3840);
  gemm128_x3<<<dim3(30, 32), 256, 0, stream>>>(x_hi, x_lo, wqt_hi, wqt_lo,
                                               b_qkv, qf, kf, vf, 4096, 3840, 1280);
  rope_pack_kernel<<<dim3(64, 16), 256, 0, stream>>>(qf, kf, cs, sn, khi, klo);
  vt_pack_kernel<<<dim3(64, 16), 256, 0, stream>>>(vf, vthi, vtlo);
  tsplit_kernel<<<dim3(40, 40), 256, 0, stream>>>(w_proj, wpt_hi, wpt_lo, 1280, 1280);
  attn_kernel<<<dim3(16, 64), 256, 0, stream>>>(qf, khi, klo, vthi, vtlo, cu, o_hi, o_lo);
  gemm128_x3<<<dim3(10, 32), 256, 0, stream>>>(o_hi, o_lo, wpt_hi, wpt_lo,
                                               b_proj, out, nullptr, nullptr, 4096, 1280, 1280);
}

// Round 5
// 412.617 us; speedup vs baseline: 2.1802x; 1.1082x over previous
//
#include <hip/hip_runtime.h>
#include <cstdint>
#include <cstddef>

typedef __bf16 bf16x8 __attribute__((ext_vector_type(8)));
typedef float f32x4 __attribute__((ext_vector_type(4)));

#define SEQ   4096
#define HID   1280
#define NH    16
#define HD    80

__device__ __forceinline__ unsigned short f2bf(float f) {
  unsigned int u = __float_as_uint(f);
  unsigned int r = u + 0x7FFFu + ((u >> 16) & 1u);   // RNE
  return (unsigned short)(r >> 16);
}
__device__ __forceinline__ float bf2f(unsigned short h) {
  return __uint_as_float(((unsigned int)h) << 16);
}
__device__ __forceinline__ __bf16 us2bf(unsigned short u) {
  union { unsigned short s; __bf16 b; } c; c.s = u; return c.b;
}
__device__ __forceinline__ void dma16(const void* g, void* l) {
  __builtin_amdgcn_global_load_lds((const __attribute__((address_space(1))) unsigned int*)g,
                                   (__attribute__((address_space(3))) unsigned int*)l, 16, 0, 0);
}

// ---------------- split: f32 -> bf16 hi only ---------------------------------
__global__ __launch_bounds__(256) void split_hi_kernel(const float* __restrict__ x,
                                                       unsigned short* __restrict__ hi,
                                                       int n4) {
  int i = blockIdx.x * 256 + threadIdx.x;
  if (i >= n4) return;
  float4 v = *((const float4*)x + i);
  *((ushort4*)hi + i) = make_ushort4(f2bf(v.x), f2bf(v.y), f2bf(v.z), f2bf(v.w));
}

// ---------------- transpose + split weights (hi/lo) --------------------------
__global__ __launch_bounds__(256) void tsplit_kernel(const float* __restrict__ W,
                                                     unsigned short* __restrict__ Thi,
                                                     unsigned short* __restrict__ Tlo,
                                                     int K, int N) {
  __shared__ float tile[32][33];
  int n0 = blockIdx.x * 32, k0 = blockIdx.y * 32;
  int tx = threadIdx.x & 31, ty = threadIdx.x >> 5;
#pragma unroll
  for (int i = 0; i < 32; i += 8)
    tile[ty + i][tx] = W[(size_t)(k0 + ty + i) * N + n0 + tx];
  __syncthreads();
#pragma unroll
  for (int i = 0; i < 32; i += 8) {
    float v = tile[tx][ty + i];
    size_t idx = (size_t)(n0 + ty + i) * K + (size_t)(k0 + tx);
    unsigned short h = f2bf(v);
    Thi[idx] = h;
    Tlo[idx] = f2bf(v - bf2f(h));
  }
}

// ---------------- 128x128 DMA GEMM, 2-term (A bf16, B hi/lo) -----------------
// A: M x K bf16 row-major. B: N x K bf16 hi/lo (W^T). Output planes of 1280
// cols each, f32, + bias. LDS 48 KB -> 3 blocks/CU.
__global__ __launch_bounds__(256, 3) void gemm128_x2(
    const unsigned short* __restrict__ A, const unsigned short* __restrict__ Bh,
    const unsigned short* __restrict__ Bl, const float* __restrict__ bias,
    float* __restrict__ out0, float* __restrict__ out1, float* __restrict__ out2,
    int M, int N, int K) {
  __shared__ __align__(16) unsigned short sALL[3 * 8192];  // [A | Bh | Bl]

  const int t = threadIdx.x;
  const int lane = t & 63, wave = t >> 6;
  const int c16 = lane & 15, quad = lane >> 4;
  const int bm = blockIdx.y * 128, bn = blockIdx.x * 128;
  const int wr = (wave >> 1) * 64, wc = (wave & 1) * 64;
  const int lrow = lane >> 3;
  const int lswz = (lane & 7) ^ lrow;

  f32x4 acc[4][4];
#pragma unroll
  for (int i = 0; i < 4; ++i)
#pragma unroll
    for (int j = 0; j < 4; ++j) acc[i][j] = (f32x4){0.f, 0.f, 0.f, 0.f};

  // 48 DMA units/iter, 12 per wave; unit ua: arr = ua>>4 (0=A,1=Bh,2=Bl)
  const unsigned short* gp[12];
#pragma unroll
  for (int i = 0; i < 12; ++i) {
    const int ua = wave * 12 + i;
    const int arr = ua >> 4, sub = ua & 15;
    const unsigned short* g = (arr == 0) ? A : (arr == 1) ? Bh : Bl;
    const int rowg = ((arr == 0) ? bm : bn) + sub * 8 + lrow;
    gp[i] = g + (size_t)rowg * K + lswz * 8;
  }

  for (int k0 = 0; k0 < K; k0 += 64) {
    __syncthreads();
#pragma unroll
    for (int i = 0; i < 12; ++i)
      dma16(gp[i] + k0, &sALL[(wave * 12 + i) * 512]);
    __syncthreads();
#pragma unroll
    for (int ks = 0; ks < 2; ++ks) {
      bf16x8 a[4], bh[4], bl[4];
#pragma unroll
      for (int mi = 0; mi < 4; ++mi) {
        const int row = wr + mi * 16 + c16;
        const int off = row * 64 + (((ks * 4 + quad) ^ (row & 7)) * 8);
        a[mi] = *(const bf16x8*)&sALL[off];
      }
#pragma unroll
      for (int ni = 0; ni < 4; ++ni) {
        const int row = wc + ni * 16 + c16;
        const int off = row * 64 + (((ks * 4 + quad) ^ (row & 7)) * 8);
        bh[ni] = *(const bf16x8*)&sALL[8192 + off];
        bl[ni] = *(const bf16x8*)&sALL[16384 + off];
      }
#pragma unroll
      for (int mi = 0; mi < 4; ++mi)
#pragma unroll
        for (int ni = 0; ni < 4; ++ni) {
          acc[mi][ni] = __builtin_amdgcn_mfma_f32_16x16x32_bf16(a[mi], bh[ni], acc[mi][ni], 0, 0, 0);
          acc[mi][ni] = __builtin_amdgcn_mfma_f32_16x16x32_bf16(a[mi], bl[ni], acc[mi][ni], 0, 0, 0);
        }
    }
  }
  // epilogue: C/D layout col=c16, row=quad*4+r
#pragma unroll
  for (int ni = 0; ni < 4; ++ni) {
    int colg = bn + wc + ni * 16 + c16;
    float bv = bias[colg];
    float* op;
    int c = colg;
    if (c < 1280) op = out0;
    else if (c < 2560) { op = out1; c -= 1280; }
    else { op = out2; c -= 2560; }
#pragma unroll
    for (int mi = 0; mi < 4; ++mi)
#pragma unroll
      for (int r = 0; r < 4; ++r) {
        int rowg = bm + wr + mi * 16 + quad * 4 + r;
        op[(size_t)rowg * 1280 + c] = acc[mi][ni][r] + bv;
      }
  }
}

// ---------------- RoPE on q (in place, f32) + k -> packed bf16 hi/lo ---------
__global__ __launch_bounds__(256) void rope_pack_kernel(
    float* __restrict__ qf, const float* __restrict__ kf,
    const float* __restrict__ cs, const float* __restrict__ sn,
    unsigned short* __restrict__ khi, unsigned short* __restrict__ klo) {
  const int h = blockIdx.y;
  const int s = blockIdx.x * 64 + (threadIdx.x >> 2);
  const int p = threadIdx.x & 3;
  float* qrow = qf + (size_t)s * HID + h * HD;
  const float* krow = kf + (size_t)s * HID + h * HD;
  const float* cr = cs + (size_t)s * HD;
  const float* sr = sn + (size_t)s * HD;
  unsigned short* kh = khi + ((size_t)h * SEQ + s) * HD;
  unsigned short* kl = klo + ((size_t)h * SEQ + s) * HD;
#pragma unroll
  for (int j = 0; j < 10; ++j) {
    int d = 10 * p + j;           // 0..39
    float c0 = cr[d], s0 = sr[d], c1 = cr[d + 40], s1 = sr[d + 40];
    float q0 = qrow[d], q1 = qrow[d + 40];
    qrow[d]      = q0 * c0 - q1 * s0;
    qrow[d + 40] = q1 * c1 + q0 * s1;
    float k0 = krow[d], k1 = krow[d + 40];
    float kn0 = k0 * c0 - k1 * s0;
    float kn1 = k1 * c1 + k0 * s1;
    unsigned short h0 = f2bf(kn0), h1 = f2bf(kn1);
    kh[d] = h0;      kl[d] = f2bf(kn0 - bf2f(h0));
    kh[d + 40] = h1; kl[d + 40] = f2bf(kn1 - bf2f(h1));
  }
}

// ---------------- pack V^T: f32 [s][1280] -> bf16 hi/lo [h][80][4096] --------
__global__ __launch_bounds__(256) void vt_pack_kernel(const float* __restrict__ vf,
                                                      unsigned short* __restrict__ vthi,
                                                      unsigned short* __restrict__ vtlo,
                                                      unsigned int* __restrict__ ctr) {
  if (blockIdx.x == 0 && blockIdx.y == 0 && threadIdx.x == 0) *ctr = 0u;
  __shared__ unsigned short sTh[80][72];
  __shared__ unsigned short sTl[80][72];
  const int h = blockIdx.y;
  const int s0 = blockIdx.x * 64;
  const int t = threadIdx.x;
  {
    int row = t >> 2, p = (t & 3) * 20;
    const float* src = vf + (size_t)(s0 + row) * HID + h * HD + p;
#pragma unroll
    for (int i = 0; i < 5; ++i) {
      float4 v = *(const float4*)(src + 4 * i);
      float vv[4] = {v.x, v.y, v.z, v.w};
#pragma unroll
      for (int j = 0; j < 4; ++j) {
        int d = p + 4 * i + j;
        unsigned short hu = f2bf(vv[j]);
        sTh[d][row] = hu;
        sTl[d][row] = f2bf(vv[j] - bf2f(hu));
      }
    }
  }
  __syncthreads();
  if (t < 160) {
    int d = t >> 1, half = (t & 1) * 32;
    size_t base = (size_t)(h * HD + d) * SEQ + s0 + half;
#pragma unroll
    for (int i = 0; i < 8; ++i) {
      *(ushort4*)&vthi[base + 4 * i] = *(ushort4*)&sTh[d][half + 4 * i];
      *(ushort4*)&vtlo[base + 4 * i] = *(ushort4*)&sTl[d][half + 4 * i];
    }
  }
}

// ---------------- attention: S^T MFMA, bpermute P-transform, pipelined DMA ---
// 768 blocks, dynamic work queue over 1024 units (u>>6 = head, u&63 = q-tile).
__global__ __launch_bounds__(256, 3) void attn_kernel(
    const float* __restrict__ qf, const unsigned short* __restrict__ khi,
    const unsigned short* __restrict__ klo, const unsigned short* __restrict__ vthi,
    const unsigned short* __restrict__ vtlo, const int* __restrict__ cu,
    unsigned short* __restrict__ ohi, unsigned int* __restrict__ ctr) {
  __shared__ __align__(16) unsigned short sKh[5120], sKl[5120];
  __shared__ __align__(16) unsigned short sVh[5120], sVl[5120];
  __shared__ int cu_s[9];
  __shared__ unsigned int s_u;

  const int t = threadIdx.x;
  const int lane = t & 63, wave = t >> 6;
  const int c16 = lane & 15, quad = lane >> 4;
  const int lr8 = lane >> 3;
  const int vswz = (lane & 7) ^ lr8;
  // bpermute byte-addrs for the C->A transpose (j<4 / j>=4)
  const int addrA = ((((2 * quad) & 3) * 16) + c16) << 2;
  const int addrB = ((((2 * quad + 1) & 3) * 16) + c16) << 2;

  if (t < 9) cu_s[t] = cu[t];

  for (;;) {
    __syncthreads();                       // prev unit fully done with LDS
    if (t == 0) s_u = atomicAdd(ctr, 1u);
    __syncthreads();
    const unsigned int u = s_u;
    if (u >= 1024u) break;
    const int h = (int)(u >> 6);
    const int r0 = (int)(u & 63u) * 64;

    const int q_my = r0 + wave * 16 + c16;     // this lane's query row
    int sq = 0, sg0 = 0, sg1 = 0;
#pragma unroll
    for (int i = 1; i < 8; ++i) {
      sq  += (q_my    >= cu_s[i]) ? 1 : 0;
      sg0 += (r0      >= cu_s[i]) ? 1 : 0;
      sg1 += (r0 + 63 >= cu_s[i]) ? 1 : 0;
    }
    const int kb_lo = cu_s[sq], kb_hi = cu_s[sq + 1];  // per-lane valid key range
    const int ck0 = cu_s[sg0] & ~63;
    const int kend = cu_s[sg1 + 1];
    const int nchunk = (kend - ck0 + 63) >> 6;

    // Q fragments (B-operand layout), scale folded
    const float qsc = 0.11180339887498949f;
    bf16x8 qh[3], ql[3];
    {
      const float* qrow = qf + (size_t)q_my * HID + h * HD;
#pragma unroll
      for (int ks = 0; ks < 3; ++ks) {
        const int d = ks * 32 + quad * 8;
        bf16x8 hf = {}, lf = {};
        if (d < 80) {
          float4 v0 = *(const float4*)(qrow + d);
          float4 v1 = *(const float4*)(qrow + d + 4);
          float vv[8] = {v0.x, v0.y, v0.z, v0.w, v1.x, v1.y, v1.z, v1.w};
#pragma unroll
          for (int j = 0; j < 8; ++j) {
            float v = vv[j] * qsc;
            unsigned short hu = f2bf(v);
            hf[j] = us2bf(hu);
            lf[j] = us2bf(f2bf(v - bf2f(hu)));
          }
        }
        qh[ks] = hf; ql[ks] = lf;
      }
    }

    f32x4 O[5];
#pragma unroll
    for (int dt = 0; dt < 5; ++dt) O[dt] = (f32x4){0.f, 0.f, 0.f, 0.f};
    float m_i = -1e30f, l_i = 0.f;

    // prologue: stage K+V of chunk 0
    {
      const unsigned short* gk = (wave & 2) ? klo : khi;
      unsigned short* lk = ((wave & 2) ? sKl : sKh) + (wave & 1) * 2560;
      const size_t kb = ((size_t)h * SEQ + ck0) * 80 + (size_t)(wave & 1) * 2560 + lane * 8;
#pragma unroll
      for (int i2 = 0; i2 < 5; ++i2) dma16(gk + kb + i2 * 512, lk + i2 * 512);
      const unsigned short* gv = (wave & 2) ? vtlo : vthi;
      unsigned short* lv = (wave & 2) ? sVl : sVh;
      const int u0 = (wave & 1) * 5;
#pragma unroll
      for (int i2 = 0; i2 < 5; ++i2) {
        const int uu = u0 + i2;
        dma16(gv + (size_t)(h * HD + 8 * uu + lr8) * SEQ + ck0 + vswz * 8, lv + uu * 512);
      }
    }
    __syncthreads();

    for (int ci = 0; ci < nchunk; ++ci) {
      const int ck = ck0 + ci * 64;
      // ---- QK: S^T = K * Q^T (C layout: col=c16=query, row=quad*4+r=key) ----
      f32x4 sc[4];
#pragma unroll
      for (int nt = 0; nt < 4; ++nt) sc[nt] = (f32x4){0.f, 0.f, 0.f, 0.f};
#pragma unroll
      for (int nt = 0; nt < 4; ++nt) {
        const int krow = nt * 16 + c16;
#pragma unroll
        for (int ks = 0; ks < 3; ++ks) {
          const int d = ks * 32 + quad * 8;
          bf16x8 kh = {}, kl = {};
          if (d < 80) {
            kh = *(const bf16x8*)&sKh[krow * 80 + d];
            kl = *(const bf16x8*)&sKl[krow * 80 + d];
          }
          sc[nt] = __builtin_amdgcn_mfma_f32_16x16x32_bf16(kh, qh[ks], sc[nt], 0, 0, 0);
          sc[nt] = __builtin_amdgcn_mfma_f32_16x16x32_bf16(kh, ql[ks], sc[nt], 0, 0, 0);
          sc[nt] = __builtin_amdgcn_mfma_f32_16x16x32_bf16(kl, qh[ks], sc[nt], 0, 0, 0);
        }
      }
      // ---- mask + online softmax, all in registers ----
      float mx = -1e30f;
#pragma unroll
      for (int nt = 0; nt < 4; ++nt)
#pragma unroll
        for (int r = 0; r < 4; ++r) {
          const int kg = ck + nt * 16 + quad * 4 + r;
          const bool ok = (kg >= kb_lo) && (kg < kb_hi);
          float v = ok ? sc[nt][r] : -1e30f;
          sc[nt][r] = v;
          mx = fmaxf(mx, v);
        }
      mx = fmaxf(mx, __shfl_xor(mx, 16));
      mx = fmaxf(mx, __shfl_xor(mx, 32));
      const float mnew = fmaxf(m_i, mx);
      const float alpha = __expf(m_i - mnew);
      float ps = 0.f;
      unsigned int pk[4][4];
#pragma unroll
      for (int nt = 0; nt < 4; ++nt)
#pragma unroll
        for (int r = 0; r < 4; ++r) {
          const float s = sc[nt][r];
          const float p = (s > -1e29f) ? __expf(s - mnew) : 0.f;
          ps += p;
          const unsigned int pu = __float_as_uint(p);
          const unsigned short ph = (unsigned short)(pu >> 16);      // trunc split
          const unsigned short pl = f2bf(p - bf2f(ph));
          pk[nt][r] = (unsigned int)ph | ((unsigned int)pl << 16);
        }
      ps += __shfl_xor(ps, 16);
      ps += __shfl_xor(ps, 32);
      l_i = l_i * alpha + ps;
      m_i = mnew;
      // alpha for query rows quad*4+r via bpermute (src lane = query id)
      float aR[4];
#pragma unroll
      for (int r = 0; r < 4; ++r)
        aR[r] = __uint_as_float((unsigned)__builtin_amdgcn_ds_bpermute(
                    (quad * 4 + r) << 2, __float_as_int(alpha)));
#pragma unroll
      for (int dt = 0; dt < 5; ++dt) {
        f32x4 o = O[dt];
        o[0] *= aR[0]; o[1] *= aR[1]; o[2] *= aR[2]; o[3] *= aR[3];
        O[dt] = o;
      }
      // ---- barrier A: all QK reads of sK done; V(i) DMA drained ----
      __syncthreads();
      if (ci + 1 < nchunk) {  // issue K(i+1): rides PV below
        const unsigned short* gk = (wave & 2) ? klo : khi;
        unsigned short* lk = ((wave & 2) ? sKl : sKh) + (wave & 1) * 2560;
        const size_t kb = ((size_t)h * SEQ + ck + 64) * 80 + (size_t)(wave & 1) * 2560 + lane * 8;
#pragma unroll
        for (int i2 = 0; i2 < 5; ++i2) dma16(gk + kb + i2 * 512, lk + i2 * 512);
      }
      // ---- PV: A = P via bpermute transpose, B = V^T (swizzled) ----
#pragma unroll
      for (int ks = 0; ks < 2; ++ks) {
        unsigned int vj[8];
#pragma unroll
        for (int j = 0; j < 8; ++j) {
          const int addr = (j < 4) ? addrA : addrB;
          const int r = j & 3;
          const int v0 = __builtin_amdgcn_ds_bpermute(addr, (int)pk[2 * ks + 0][r]);
          const int v1 = __builtin_amdgcn_ds_bpermute(addr, (int)pk[2 * ks + 1][r]);
          vj[j] = (unsigned int)((quad & 2) ? v1 : v0);
        }
        union { unsigned int w[4]; bf16x8 v; } ph, pl;
        ph.w[0] = __builtin_amdgcn_perm(vj[1], vj[0], 0x05040100u);
        ph.w[1] = __builtin_amdgcn_perm(vj[3], vj[2], 0x05040100u);
        ph.w[2] = __builtin_amdgcn_perm(vj[5], vj[4], 0x05040100u);
        ph.w[3] = __builtin_amdgcn_perm(vj[7], vj[6], 0x05040100u);
        pl.w[0] = __builtin_amdgcn_perm(vj[1], vj[0], 0x07060302u);
        pl.w[1] = __builtin_amdgcn_perm(vj[3], vj[2], 0x07060302u);
        pl.w[2] = __builtin_amdgcn_perm(vj[5], vj[4], 0x07060302u);
        pl.w[3] = __builtin_amdgcn_perm(vj[7], vj[6], 0x07060302u);
        const int g = ks * 4 + quad;
#pragma unroll
        for (int dt = 0; dt < 5; ++dt) {
          const int d = dt * 16 + c16;
          const int off = d * 64 + ((g ^ (d & 7)) * 8);
          bf16x8 vh = *(const bf16x8*)&sVh[off];
          bf16x8 vl = *(const bf16x8*)&sVl[off];
          O[dt] = __builtin_amdgcn_mfma_f32_16x16x32_bf16(ph.v, vh, O[dt], 0, 0, 0);
          O[dt] = __builtin_amdgcn_mfma_f32_16x16x32_bf16(ph.v, vl, O[dt], 0, 0, 0);
          O[dt] = __builtin_amdgcn_mfma_f32_16x16x32_bf16(pl.v, vh, O[dt], 0, 0, 0);
        }
      }
      // ---- barrier B: all PV reads of sV done; K(i+1) DMA drained ----
      __syncthreads();
      if (ci + 1 < nchunk) {  // issue V(i+1): rides next QK+softmax
        const unsigned short* gv = (wave & 2) ? vtlo : vthi;
        unsigned short* lv = (wave & 2) ? sVl : sVh;
        const int u0 = (wave & 1) * 5;
#pragma unroll
        for (int i2 = 0; i2 < 5; ++i2) {
          const int uu = u0 + i2;
          dma16(gv + (size_t)(h * HD + 8 * uu + lr8) * SEQ + (ck + 64) + vswz * 8, lv + uu * 512);
        }
      }
    }
    // ---- epilogue: normalize + store o_hi (bf16) ----
    const float inv = 1.0f / l_i;
    float iR[4];
#pragma unroll
    for (int r = 0; r < 4; ++r)
      iR[r] = __uint_as_float((unsigned)__builtin_amdgcn_ds_bpermute(
                  (quad * 4 + r) << 2, __float_as_int(inv)));
#pragma unroll
    for (int dt = 0; dt < 5; ++dt)
#pragma unroll
      for (int r = 0; r < 4; ++r) {
        const int rowg = r0 + wave * 16 + quad * 4 + r;
        ohi[(size_t)rowg * HID + h * HD + dt * 16 + c16] = f2bf(O[dt][r] * iR[r]);
      }
  }
}

// ---------------- host launcher ---------------------------------------------
extern "C" void kernel_launch(void* const* d_in, const int* in_sizes, int n_in,
                              void* d_out, int out_size, void* d_ws, size_t ws_size,
                              hipStream_t stream) {
  const float* x      = (const float*)d_in[0];
  const int*   cu     = (const int*)d_in[1];
  const float* cs     = (const float*)d_in[2];
  const float* sn     = (const float*)d_in[3];
  const float* w_qkv  = (const float*)d_in[4];
  const float* b_qkv  = (const float*)d_in[5];
  const float* w_proj = (const float*)d_in[6];
  const float* b_proj = (const float*)d_in[7];
  float* out = (float*)d_out;

  char* ws = (char*)d_ws;
  // layout (bytes), lifetime overlays:
  //  [0,      20.97M)  qf f32                         (gemm1 -> attn)
  //  [20.97M, 41.94M)  kf f32      -> vthi/vtlo       (rope_pack, then vt_pack out)
  //  [41.94M, 62.91M)  vf f32      -> o_hi            (vt_pack in, then attn out)
  //  [62.91M, 73.40M)  x_hi bf16   -> khi             (gemm1 in, then rope out)
  //  [73.40M, 83.89M)  klo
  //  [83.89M, 103.55M) wqt hi/lo   -> ctr (4B)        (gemm1 in, then queue ctr)
  //  [103.55M,110.10M) wpt hi/lo                      (gemm2 in)
  float*          qf     = (float*)(ws + 0);
  float*          kf     = (float*)(ws + 20971520ULL);
  unsigned short* vthi   = (unsigned short*)(ws + 20971520ULL);
  unsigned short* vtlo   = (unsigned short*)(ws + 31457280ULL);
  float*          vf     = (float*)(ws + 41943040ULL);
  unsigned short* o_hi   = (unsigned short*)(ws + 41943040ULL);
  unsigned short* x_hi   = (unsigned short*)(ws + 62914560ULL);
  unsigned short* khi    = (unsigned short*)(ws + 62914560ULL);
  unsigned short* klo    = (unsigned short*)(ws + 73400320ULL);
  unsigned short* wqt_hi = (unsigned short*)(ws + 83886080ULL);
  unsigned short* wqt_lo = (unsigned short*)(ws + 93716480ULL);
  unsigned short* wpt_hi = (unsigned short*)(ws + 103546880ULL);
  unsigned short* wpt_lo = (unsigned short*)(ws + 106823680ULL);
  unsigned int*   ctr    = (unsigned int*)(ws + 83886080ULL);  // over dead wqt_hi

  split_hi_kernel<<<5120, 256, 0, stream>>>(x, x_hi, 1310720);
  tsplit_kernel<<<dim3(120, 40), 256, 0, stream>>>(w_qkv, wqt_hi, wqt_lo, 1280, 3840);
  tsplit_kernel<<<dim3(40, 40), 256, 0, stream>>>(w_proj, wpt_hi, wpt_lo, 1280, 1280);
  gemm128_x2<<<dim3(30, 32), 256, 0, stream>>>(x_hi, wqt_hi, wqt_lo, b_qkv,
                                               qf, kf, vf, 4096, 3840, 1280);
  rope_pack_kernel<<<dim3(64, 16), 256, 0, stream>>>(qf, kf, cs, sn, khi, klo);
  vt_pack_kernel<<<dim3(64, 16), 256, 0, stream>>>(vf, vthi, vtlo, ctr);
  attn_kernel<<<768, 256, 0, stream>>>(qf, khi, klo, vthi, vtlo, cu, o_hi, ctr);
  gemm128_x2<<<dim3(10, 32), 256, 0, stream>>>(o_hi, wpt_hi, wpt_lo, b_proj,
                                               out, nullptr, nullptr, 4096, 1280, 1280);
}